// Round 14
// baseline (239.241 us; speedup 1.0000x reference)
//
#include <hip/hip_runtime.h>
#include <math.h>

// Problem constants (fixed by reference setup_inputs)
constexpr int B = 2, C = 16, H = 160, W = 192, S = 3, D = 48;
constexpr int HW = H * W;          // 30720 = 120 * 256
constexpr int SB = S * B;

// ------------------------------------------------------------------
// Setup kernel: per (s,b) fold projection chain into
//   A = Ks * R * inv(Kref) (3x3 f64), q = Ks * t (f64)
// so main kernel does p = depth*(A*[u,v,1]) + q.
// ws layout: (s*B+b)*12 doubles = [A row-major 0..8][q 9..11]
// ------------------------------------------------------------------
__global__ void precompute_mats(const float* __restrict__ ref_intr,
                                const float* __restrict__ src_intr,
                                const float* __restrict__ ref_to_src,
                                double* __restrict__ ws)
{
    const int i = threadIdx.x;
    if (i >= SB) return;
    const int b = i % B;

    const float* Kp = ref_intr + b * 9;
    const double a00 = Kp[0], a01 = Kp[1], a02 = Kp[2];
    const double a10 = Kp[3], a11 = Kp[4], a12 = Kp[5];
    const double a20 = Kp[6], a21 = Kp[7], a22 = Kp[8];
    const double c00 =  (a11 * a22 - a12 * a21);
    const double c01 = -(a10 * a22 - a12 * a20);
    const double c02 =  (a10 * a21 - a11 * a20);
    const double c10 = -(a01 * a22 - a02 * a21);
    const double c11 =  (a00 * a22 - a02 * a20);
    const double c12 = -(a00 * a21 - a01 * a20);
    const double c20 =  (a01 * a12 - a02 * a11);
    const double c21 = -(a00 * a12 - a02 * a10);
    const double c22 =  (a00 * a11 - a01 * a10);
    const double invdet = 1.0 / (a00 * c00 + a01 * c01 + a02 * c02);
    const double iK[9] = { c00 * invdet, c10 * invdet, c20 * invdet,
                           c01 * invdet, c11 * invdet, c21 * invdet,
                           c02 * invdet, c12 * invdet, c22 * invdet };

    const float* Tp = ref_to_src + i * 16;
    const float* Ks = src_intr + i * 9;

    double M[9];  // R * inv(K)
    #pragma unroll
    for (int r = 0; r < 3; ++r)
        #pragma unroll
        for (int c = 0; c < 3; ++c)
            M[r * 3 + c] = (double)Tp[r * 4 + 0] * iK[0 + c]
                         + (double)Tp[r * 4 + 1] * iK[3 + c]
                         + (double)Tp[r * 4 + 2] * iK[6 + c];

    double* o = ws + i * 12;
    #pragma unroll
    for (int r = 0; r < 3; ++r) {
        #pragma unroll
        for (int c = 0; c < 3; ++c)
            o[r * 3 + c] = (double)Ks[r * 3 + 0] * M[0 + c]
                         + (double)Ks[r * 3 + 1] * M[3 + c]
                         + (double)Ks[r * 3 + 2] * M[6 + c];
        o[9 + r] = (double)Ks[r * 3 + 0] * (double)Tp[3]
                 + (double)Ks[r * 3 + 1] * (double)Tp[7]
                 + (double)Ks[r * 3 + 2] * (double)Tp[11];
    }
}

// ------------------------------------------------------------------
// Main kernel = R11 skeleton (best: 108.8us) + cross-lane tap sharing.
//
// Carried rules: 2D grid (R4: b/d/s wave-uniform -> saddr loads);
// NCHW stride-1 (R3); NO min-waves bounds (R2/R5: spill storms);
// FULL unroll (R10/R12: partial unroll starves the load window);
// no unaligned vector loads (R13: 52% regression); f1-fold + shifted
// variance (R10/R11-validated numerics).
//
// Round-14: waves never straddle ref rows (W = 192 = 3*64), adjacent
// lanes sample adjacent src pixels -> lane i's tap01 value IS lane
// i+1's tap00 whenever x0c(i+1) == x0c(i)+1 and the rows match.
// Replace tap01/tap11 LOADS with __shfl_down(v00/v10, 1) + a per-
// channel exec-masked fallback branch (lane 63, x-clamp plateaus,
// row mismatch). Masked loads fetch lines only for active lanes, and
// those are clamp-collapsed (1 line). Cuts redundant L1 line re-reads
// ~37%/wave. Values bit-identical (same address, same value) ->
// absmax unchanged.
// ------------------------------------------------------------------
__global__ __launch_bounds__(256) void plane_sweep_kernel(
    const float* __restrict__ ref_feats,   // [B,C,H,W]
    const float* __restrict__ src_feats,   // [S,B,C,H,W]
    const float* __restrict__ depths,      // [D]
    const double* __restrict__ mats,       // [SB][12]
    float* __restrict__ out)               // [B,D,H,W]
{
    const int pix = blockIdx.x * 256 + threadIdx.x;   // HW = 120*256 exact
    const int by  = blockIdx.y;                       // b*D + d (scalar)
    const int d   = by % D;                           // scalar
    const int b   = by / D;                           // scalar

    const int w = pix % W;
    const int h = pix / W;
    const int lane = threadIdx.x & 63;

    // ---- ref stats WITHOUT storing f1: m1, n1 in one pass ----
    const float* rb = ref_feats + (size_t)b * C * HW;
    float sum1 = 0.0f, sqr1 = 0.0f;
    #pragma unroll
    for (int c = 0; c < C; ++c) {
        const float rc = rb[c * HW + pix];
        sum1 += rc;
        sqr1 = fmaf(rc, rc, sqr1);
    }
    const float m1 = sum1 * (1.0f / C);
    float sq1 = fmaf(-sum1, m1, sqr1);     // Σ(r-m1)² = Σr² - sum1·m1
    sq1 = fmaxf(sq1, 0.0f);
    const float n1 = sqrtf(sq1);

    const double u = (double)w, v = (double)h;
    const double depth = (double)depths[d];    // scalar load
    float cost = 0.0f;

    #pragma unroll 1   // one source's f64 state live at a time; s uniform
    for (int s = 0; s < S; ++s) {
        const double* Aq = mats + (s * B + b) * 12;   // scalar loads
        const double rx = fma(u, Aq[0], fma(v, Aq[1], Aq[2]));
        const double ry = fma(u, Aq[3], fma(v, Aq[4], Aq[5]));
        const double rz = fma(u, Aq[6], fma(v, Aq[7], Aq[8]));

        const double p0 = fma(depth, rx, Aq[9]);
        const double p1 = fma(depth, ry, Aq[10]);
        const double p2 = fma(depth, rz, Aq[11]);

        const bool valid = p2 > 0.001;
        const double zs = fmax(p2, 0.001);
        // f64 reciprocal: v_rcp_f64 approx + 1 Newton step (>=2^-28 rel)
#if __has_builtin(__builtin_amdgcn_rcp)
        double r = __builtin_amdgcn_rcp(zs);
#else
        double r = (double)__builtin_amdgcn_rcpf((float)zs);
        r = r * fma(-zs, r, 2.0);
#endif
        r = r * fma(-zs, r, 2.0);
        const double x = p0 * r;
        const double y = p1 * r;

        const double x0f = floor(x);
        const double y0f = floor(y);
        // sub-pixel fractions -> f32 (f64 x,y already ~1e-12-accurate)
        const float fx = (float)(x - x0f);
        const float fy = (float)(y - y0f);
        const int x0 = (int)x0f;
        const int y0 = (int)y0f;
        const int x1 = x0 + 1;
        const int y1 = y0 + 1;

        const float gx = 1.0f - fx, gy = 1.0f - fy;
        const bool okx0 = (x0 >= 0) & (x0 < W);
        const bool okx1 = (x1 >= 0) & (x1 < W);
        const bool oky0 = (y0 >= 0) & (y0 < H);
        const bool oky1 = (y1 >= 0) & (y1 < H);
        const float w00 = (valid & okx0 & oky0) ? gx * gy : 0.0f;
        const float w01 = (valid & okx1 & oky0) ? fx * gy : 0.0f;
        const float w10 = (valid & okx0 & oky1) ? gx * fy : 0.0f;
        const float w11 = (valid & okx1 & oky1) ? fx * fy : 0.0f;

        const int x0c = min(max(x0, 0), W - 1);
        const int x1c = min(max(x1, 0), W - 1);
        const int y0c = min(max(y0, 0), H - 1);
        const int y1c = min(max(y1, 0), H - 1);
        const int off00 = y0c * W + x0c;
        const int off01 = y0c * W + x1c;
        const int off10 = y1c * W + x0c;
        const int off11 = y1c * W + x1c;

        // ---- cross-lane share eligibility (once per s) ----
        // lane i can take v01 = shfl_down(v00): needs lane i+1's tap00
        // at (y0c, x0c+1), and our x1c to actually be x0c+1.
        const int x0n = __shfl_down(x0c, 1);
        const int y0n = __shfl_down(y0c, 1);
        const int y1n = __shfl_down(y1c, 1);
        const bool ok = (lane != 63) & (x0n == x0c + 1) & (x1c == x0c + 1)
                      & (y0n == y0c) & (y1n == y1c);

        // sb wave-uniform -> saddr loads; channel walks in SALU
        const float* sb = src_feats + (size_t)(s * B + b) * C * HW;

        // ---- fused pass: bilinear + shifted-variance stats + rdot ----
        // c = 0 peeled (compile-time shift init).
        float rdot, st = 0.0f, s2 = 0.0f, av;
        {
            const float rc = rb[pix];
            const float v00 = sb[off00];
            const float v10 = sb[off10];
            float v01 = __shfl_down(v00, 1);
            float v11 = __shfl_down(v10, 1);
            if (!ok) {                      // exec-masked: lines only for
                v01 = sb[off01];            // the few fallback lanes
                v11 = sb[off11];
            }
            const float val = w00 * v00 + w01 * v01 + w10 * v10 + w11 * v11;
            av = val;
            rdot = rc * val;
        }
        #pragma unroll   // FULL unroll: one contiguous load window per s
        for (int c = 1; c < C; ++c) {
            const float* p = sb + c * HW;
            const float rc = rb[c * HW + pix];
            const float v00 = p[off00];
            const float v10 = p[off10];
            float v01 = __shfl_down(v00, 1);
            float v11 = __shfl_down(v10, 1);
            if (!ok) {
                v01 = p[off01];
                v11 = p[off11];
            }
            const float val = w00 * v00 + w01 * v01 + w10 * v10 + w11 * v11;
            const float t = val - av;
            st += t;
            s2 = fmaf(t, t, s2);
            rdot = fmaf(rc, val, rdot);
        }
        // Σval = st + C·av ; dot = Σrc·val - m1·Σval ;
        // Σ(f2-m2)² = s2 - st²/C (shifted form; clamp rounding negatives)
        const float sv = fmaf((float)C, av, st);
        const float dot = fmaf(-m1, sv, rdot);
        float sq2 = fmaf(-st * (1.0f / C), st, s2);
        sq2 = fmaxf(sq2, 0.0f);
        cost += dot / (n1 * sqrtf(sq2) + 1e-6f);
    }

    // out base wave-uniform -> saddr store with voffset pix*4
    out[(size_t)by * HW + pix] = cost * (1.0f / S);
}

extern "C" void kernel_launch(void* const* d_in, const int* in_sizes, int n_in,
                              void* d_out, int out_size, void* d_ws, size_t ws_size,
                              hipStream_t stream) {
    const float* ref_feats  = (const float*)d_in[0];
    const float* src_feats  = (const float*)d_in[1];
    const float* ref_intr   = (const float*)d_in[2];
    const float* src_intr   = (const float*)d_in[3];
    const float* ref_to_src = (const float*)d_in[4];
    const float* depths     = (const float*)d_in[5];
    float* out = (float*)d_out;
    double* mats = (double*)d_ws;   // needs SB*12*8 = 576 bytes

    precompute_mats<<<1, 64, 0, stream>>>(ref_intr, src_intr, ref_to_src, mats);

    dim3 grid(HW / 256, B * D);     // 120 x 96, exact
    plane_sweep_kernel<<<grid, dim3(256), 0, stream>>>(
        ref_feats, src_feats, depths, mats, out);
}

// Round 15
// 165.122 us; speedup vs baseline: 1.4489x; 1.4489x over previous
//
#include <hip/hip_runtime.h>
#include <math.h>

// Problem constants (fixed by reference setup_inputs)
constexpr int B = 2, C = 16, H = 160, W = 192, S = 3, D = 48;
constexpr int HW = H * W;          // 30720 = 120 * 256
constexpr int SB = S * B;

// Workspace layout: [0,576) f64 mats; [1024, 1024+B*HW*8) f32x2 ref stats
constexpr size_t STATS_OFF = 1024;
constexpr size_t WS_NEEDED = STATS_OFF + (size_t)B * HW * 2 * sizeof(float);

// ------------------------------------------------------------------
// Setup kernel: per (s,b) fold projection chain into
//   A = Ks * R * inv(Kref) (3x3 f64), q = Ks * t (f64)
// so main kernel does p = depth*(A*[u,v,1]) + q.
// ws layout: (s*B+b)*12 doubles = [A row-major 0..8][q 9..11]
// ------------------------------------------------------------------
__global__ void precompute_mats(const float* __restrict__ ref_intr,
                                const float* __restrict__ src_intr,
                                const float* __restrict__ ref_to_src,
                                double* __restrict__ ws)
{
    const int i = threadIdx.x;
    if (i >= SB) return;
    const int b = i % B;

    const float* Kp = ref_intr + b * 9;
    const double a00 = Kp[0], a01 = Kp[1], a02 = Kp[2];
    const double a10 = Kp[3], a11 = Kp[4], a12 = Kp[5];
    const double a20 = Kp[6], a21 = Kp[7], a22 = Kp[8];
    const double c00 =  (a11 * a22 - a12 * a21);
    const double c01 = -(a10 * a22 - a12 * a20);
    const double c02 =  (a10 * a21 - a11 * a20);
    const double c10 = -(a01 * a22 - a02 * a21);
    const double c11 =  (a00 * a22 - a02 * a20);
    const double c12 = -(a00 * a21 - a01 * a20);
    const double c20 =  (a01 * a12 - a02 * a11);
    const double c21 = -(a00 * a12 - a02 * a10);
    const double c22 =  (a00 * a11 - a01 * a10);
    const double invdet = 1.0 / (a00 * c00 + a01 * c01 + a02 * c02);
    const double iK[9] = { c00 * invdet, c10 * invdet, c20 * invdet,
                           c01 * invdet, c11 * invdet, c21 * invdet,
                           c02 * invdet, c12 * invdet, c22 * invdet };

    const float* Tp = ref_to_src + i * 16;
    const float* Ks = src_intr + i * 9;

    double M[9];  // R * inv(K)
    #pragma unroll
    for (int r = 0; r < 3; ++r)
        #pragma unroll
        for (int c = 0; c < 3; ++c)
            M[r * 3 + c] = (double)Tp[r * 4 + 0] * iK[0 + c]
                         + (double)Tp[r * 4 + 1] * iK[3 + c]
                         + (double)Tp[r * 4 + 2] * iK[6 + c];

    double* o = ws + i * 12;
    #pragma unroll
    for (int r = 0; r < 3; ++r) {
        #pragma unroll
        for (int c = 0; c < 3; ++c)
            o[r * 3 + c] = (double)Ks[r * 3 + 0] * M[0 + c]
                         + (double)Ks[r * 3 + 1] * M[3 + c]
                         + (double)Ks[r * 3 + 2] * M[6 + c];
        o[9 + r] = (double)Ks[r * 3 + 0] * (double)Tp[3]
                 + (double)Ks[r * 3 + 1] * (double)Tp[7]
                 + (double)Ks[r * 3 + 2] * (double)Tp[11];
    }
}

// ------------------------------------------------------------------
// Ref-stats kernel: per (b,pix) compute m1, n1 ONCE (the main kernel
// recomputed them 48x per pixel). Identical op order to R11's inline
// pass -> bit-identical m1/n1 -> absmax unchanged.
// ------------------------------------------------------------------
__global__ __launch_bounds__(256) void precompute_refstats(
    const float* __restrict__ ref_feats,   // [B,C,H,W]
    float* __restrict__ stats)             // [B*HW][2] = {m1, n1}
{
    const int idx = blockIdx.x * 256 + threadIdx.x;   // B*HW = 240*256 exact
    const int b   = idx / HW;
    const int pix = idx % HW;

    const float* rb = ref_feats + (size_t)b * C * HW;
    float sum1 = 0.0f, sqr1 = 0.0f;
    #pragma unroll
    for (int c = 0; c < C; ++c) {
        const float rc = rb[c * HW + pix];
        sum1 += rc;
        sqr1 = fmaf(rc, rc, sqr1);
    }
    const float m1 = sum1 * (1.0f / C);
    float sq1 = fmaf(-sum1, m1, sqr1);     // Σ(r-m1)² = Σr² - sum1·m1
    sq1 = fmaxf(sq1, 0.0f);
    const float n1 = sqrtf(sq1);

    stats[idx * 2 + 0] = m1;
    stats[idx * 2 + 1] = n1;   // 8B-aligned pair -> one dwordx2 in main
}

// ------------------------------------------------------------------
// Main kernel = R11 (best: 108.8us) with the stats pass replaced by a
// 2-float load (PRE=true). Everything else byte-for-byte R11.
//
// Carried rules: 2D grid (R4: b/d/s wave-uniform -> saddr loads);
// NCHW stride-1 (R3: NHWC gathers amplify L1 4x); NO min-waves bounds
// (R2/R5: spill storms); FULL unroll, flat INDEPENDENT load stream
// (R10/R12: partial unroll starves the window; R13: unaligned pair
// loads -52%; R14: shfl+divergent fallback serializes the stream —
// any structural deviation from the flat stream costs 30-70%).
// f1-fold + shifted variance (R10/R11-validated numerics).
// ------------------------------------------------------------------
template<bool PRE>
__global__ __launch_bounds__(256) void plane_sweep_kernel(
    const float* __restrict__ ref_feats,   // [B,C,H,W]
    const float* __restrict__ src_feats,   // [S,B,C,H,W]
    const float* __restrict__ depths,      // [D]
    const double* __restrict__ mats,       // [SB][12]
    const float* __restrict__ stats,       // [B*HW][2] (PRE only)
    float* __restrict__ out)               // [B,D,H,W]
{
    const int pix = blockIdx.x * 256 + threadIdx.x;   // HW = 120*256 exact
    const int by  = blockIdx.y;                       // b*D + d (scalar)
    const int d   = by % D;                           // scalar
    const int b   = by / D;                           // scalar

    const int w = pix % W;
    const int h = pix / W;

    const float* rb = ref_feats + (size_t)b * C * HW;

    // ---- ref stats: precomputed load, or R11 inline fallback ----
    float m1, n1;
    if (PRE) {
        const float2 s2v = *(const float2*)(stats + ((size_t)b * HW + pix) * 2);
        m1 = s2v.x;
        n1 = s2v.y;
    } else {
        float sum1 = 0.0f, sqr1 = 0.0f;
        #pragma unroll
        for (int c = 0; c < C; ++c) {
            const float rc = rb[c * HW + pix];
            sum1 += rc;
            sqr1 = fmaf(rc, rc, sqr1);
        }
        m1 = sum1 * (1.0f / C);
        float sq1 = fmaf(-sum1, m1, sqr1);
        sq1 = fmaxf(sq1, 0.0f);
        n1 = sqrtf(sq1);
    }

    const double u = (double)w, v = (double)h;
    const double depth = (double)depths[d];    // scalar load
    float cost = 0.0f;

    #pragma unroll 1   // one source's f64 state live at a time; s uniform
    for (int s = 0; s < S; ++s) {
        const double* Aq = mats + (s * B + b) * 12;   // scalar loads
        const double rx = fma(u, Aq[0], fma(v, Aq[1], Aq[2]));
        const double ry = fma(u, Aq[3], fma(v, Aq[4], Aq[5]));
        const double rz = fma(u, Aq[6], fma(v, Aq[7], Aq[8]));

        const double p0 = fma(depth, rx, Aq[9]);
        const double p1 = fma(depth, ry, Aq[10]);
        const double p2 = fma(depth, rz, Aq[11]);

        const bool valid = p2 > 0.001;
        const double zs = fmax(p2, 0.001);
        // f64 reciprocal: v_rcp_f64 approx + 1 Newton step (>=2^-28 rel)
#if __has_builtin(__builtin_amdgcn_rcp)
        double r = __builtin_amdgcn_rcp(zs);
#else
        double r = (double)__builtin_amdgcn_rcpf((float)zs);
        r = r * fma(-zs, r, 2.0);
#endif
        r = r * fma(-zs, r, 2.0);
        const double x = p0 * r;
        const double y = p1 * r;

        const double x0f = floor(x);
        const double y0f = floor(y);
        // sub-pixel fractions -> f32 (f64 x,y already ~1e-12-accurate)
        const float fx = (float)(x - x0f);
        const float fy = (float)(y - y0f);
        const int x0 = (int)x0f;
        const int y0 = (int)y0f;
        const int x1 = x0 + 1;
        const int y1 = y0 + 1;

        const float gx = 1.0f - fx, gy = 1.0f - fy;
        const bool okx0 = (x0 >= 0) & (x0 < W);
        const bool okx1 = (x1 >= 0) & (x1 < W);
        const bool oky0 = (y0 >= 0) & (y0 < H);
        const bool oky1 = (y1 >= 0) & (y1 < H);
        const float w00 = (valid & okx0 & oky0) ? gx * gy : 0.0f;
        const float w01 = (valid & okx1 & oky0) ? fx * gy : 0.0f;
        const float w10 = (valid & okx0 & oky1) ? gx * fy : 0.0f;
        const float w11 = (valid & okx1 & oky1) ? fx * fy : 0.0f;

        const int x0c = min(max(x0, 0), W - 1);
        const int x1c = min(max(x1, 0), W - 1);
        const int y0c = min(max(y0, 0), H - 1);
        const int y1c = min(max(y1, 0), H - 1);
        const int off00 = y0c * W + x0c;
        const int off01 = y0c * W + x1c;
        const int off10 = y1c * W + x0c;
        const int off11 = y1c * W + x1c;

        // sb wave-uniform -> saddr loads; channel walks in SALU
        const float* sb = src_feats + (size_t)(s * B + b) * C * HW;

        // ---- fused pass: bilinear + shifted-variance stats + rdot ----
        // c = 0 peeled (compile-time shift init).
        float rdot, st = 0.0f, s2 = 0.0f, av;
        {
            const float rc = rb[pix];
            const float val = w00 * sb[off00] + w01 * sb[off01]
                            + w10 * sb[off10] + w11 * sb[off11];
            av = val;
            rdot = rc * val;
        }
        #pragma unroll   // FULL unroll: flat independent load stream
        for (int c = 1; c < C; ++c) {
            const float* p = sb + c * HW;
            const float rc = rb[c * HW + pix];
            const float v00 = p[off00];
            const float v01 = p[off01];
            const float v10 = p[off10];
            const float v11 = p[off11];
            const float val = w00 * v00 + w01 * v01 + w10 * v10 + w11 * v11;
            const float t = val - av;
            st += t;
            s2 = fmaf(t, t, s2);
            rdot = fmaf(rc, val, rdot);
        }
        // Σval = st + C·av ; dot = Σrc·val - m1·Σval ;
        // Σ(f2-m2)² = s2 - st²/C (shifted form; clamp rounding negatives)
        const float sv = fmaf((float)C, av, st);
        const float dot = fmaf(-m1, sv, rdot);
        float sq2 = fmaf(-st * (1.0f / C), st, s2);
        sq2 = fmaxf(sq2, 0.0f);
        cost += dot / (n1 * sqrtf(sq2) + 1e-6f);
    }

    // out base wave-uniform -> saddr store with voffset pix*4
    out[(size_t)by * HW + pix] = cost * (1.0f / S);
}

extern "C" void kernel_launch(void* const* d_in, const int* in_sizes, int n_in,
                              void* d_out, int out_size, void* d_ws, size_t ws_size,
                              hipStream_t stream) {
    const float* ref_feats  = (const float*)d_in[0];
    const float* src_feats  = (const float*)d_in[1];
    const float* ref_intr   = (const float*)d_in[2];
    const float* src_intr   = (const float*)d_in[3];
    const float* ref_to_src = (const float*)d_in[4];
    const float* depths     = (const float*)d_in[5];
    float* out = (float*)d_out;
    double* mats = (double*)d_ws;   // mats at ws offset 0 (576 B)

    precompute_mats<<<1, 64, 0, stream>>>(ref_intr, src_intr, ref_to_src, mats);

    dim3 grid(HW / 256, B * D);     // 120 x 96, exact

    if (ws_size >= WS_NEEDED) {
        float* stats = (float*)((char*)d_ws + STATS_OFF);
        precompute_refstats<<<(B * HW) / 256, 256, 0, stream>>>(ref_feats, stats);
        plane_sweep_kernel<true><<<grid, dim3(256), 0, stream>>>(
            ref_feats, src_feats, depths, mats, stats, out);
    } else {
        plane_sweep_kernel<false><<<grid, dim3(256), 0, stream>>>(
            ref_feats, src_feats, depths, mats, nullptr, out);
    }
}

// Round 16
// 163.486 us; speedup vs baseline: 1.4634x; 1.0100x over previous
//
#include <hip/hip_runtime.h>
#include <math.h>

// Problem constants (fixed by reference setup_inputs)
constexpr int B = 2, C = 16, H = 160, W = 192, S = 3, D = 48;
constexpr int HW = H * W;          // 30720 = 120 * 256
constexpr int SB = S * B;

// ------------------------------------------------------------------
// Setup kernel: per (s,b) fold projection chain into
//   A = Ks * R * inv(Kref) (3x3 f64), q = Ks * t (f64)
// so main kernel does p = depth*(A*[u,v,1]) + q.
// ws layout: (s*B+b)*12 doubles = [A row-major 0..8][q 9..11]
// ------------------------------------------------------------------
__global__ void precompute_mats(const float* __restrict__ ref_intr,
                                const float* __restrict__ src_intr,
                                const float* __restrict__ ref_to_src,
                                double* __restrict__ ws)
{
    const int i = threadIdx.x;
    if (i >= SB) return;
    const int b = i % B;

    const float* Kp = ref_intr + b * 9;
    const double a00 = Kp[0], a01 = Kp[1], a02 = Kp[2];
    const double a10 = Kp[3], a11 = Kp[4], a12 = Kp[5];
    const double a20 = Kp[6], a21 = Kp[7], a22 = Kp[8];
    const double c00 =  (a11 * a22 - a12 * a21);
    const double c01 = -(a10 * a22 - a12 * a20);
    const double c02 =  (a10 * a21 - a11 * a20);
    const double c10 = -(a01 * a22 - a02 * a21);
    const double c11 =  (a00 * a22 - a02 * a20);
    const double c12 = -(a00 * a21 - a01 * a20);
    const double c20 =  (a01 * a12 - a02 * a11);
    const double c21 = -(a00 * a12 - a02 * a10);
    const double c22 =  (a00 * a11 - a01 * a10);
    const double invdet = 1.0 / (a00 * c00 + a01 * c01 + a02 * c02);
    const double iK[9] = { c00 * invdet, c10 * invdet, c20 * invdet,
                           c01 * invdet, c11 * invdet, c21 * invdet,
                           c02 * invdet, c12 * invdet, c22 * invdet };

    const float* Tp = ref_to_src + i * 16;
    const float* Ks = src_intr + i * 9;

    double M[9];  // R * inv(K)
    #pragma unroll
    for (int r = 0; r < 3; ++r)
        #pragma unroll
        for (int c = 0; c < 3; ++c)
            M[r * 3 + c] = (double)Tp[r * 4 + 0] * iK[0 + c]
                         + (double)Tp[r * 4 + 1] * iK[3 + c]
                         + (double)Tp[r * 4 + 2] * iK[6 + c];

    double* o = ws + i * 12;
    #pragma unroll
    for (int r = 0; r < 3; ++r) {
        #pragma unroll
        for (int c = 0; c < 3; ++c)
            o[r * 3 + c] = (double)Ks[r * 3 + 0] * M[0 + c]
                         + (double)Ks[r * 3 + 1] * M[3 + c]
                         + (double)Ks[r * 3 + 2] * M[6 + c];
        o[9 + r] = (double)Ks[r * 3 + 0] * (double)Tp[3]
                 + (double)Ks[r * 3 + 1] * (double)Tp[7]
                 + (double)Ks[r * 3 + 2] * (double)Tp[11];
    }
}

// ------------------------------------------------------------------
// Main kernel = R11 body byte-for-byte (best: 108.8us main). ONLY the
// grid mapping changes (Round-16): blockIdx.x = b*D+d (FAST dim),
// blockIdx.y = pixel tile. The 96 consecutively-dispatched blocks are
// all depths/batches of the SAME pixel tile -> their shared src
// neighborhood (~few hundred KB) stays hot in each XCD's 4MB L2.
// Attacks the measured 3.3x HBM re-read (FETCH 58MB vs 17.7MB
// footprint) and the ~9% per-wave issue efficiency (latency-stall
// signature). Body numerics identical -> absmax unchanged.
//
// Carried rules: b/d wave-uniform -> saddr loads (R4); NCHW stride-1
// (R3); NO min-waves bounds (R2/R5: spill storms); FULL unroll, flat
// INDEPENDENT load stream (R10/R12: partial unroll starves window;
// R13: unaligned pair loads -52%; R14: shfl fallback serializes);
// f1-fold + shifted variance (R10/R11-validated); no refstats
// precompute (R15: flat on main, net-negative with launch overhead).
// ------------------------------------------------------------------
__global__ __launch_bounds__(256) void plane_sweep_kernel(
    const float* __restrict__ ref_feats,   // [B,C,H,W]
    const float* __restrict__ src_feats,   // [S,B,C,H,W]
    const float* __restrict__ depths,      // [D]
    const double* __restrict__ mats,       // [SB][12]
    float* __restrict__ out)               // [B,D,H,W]
{
    const int pix = blockIdx.y * 256 + threadIdx.x;   // HW = 120*256 exact
    const int by  = blockIdx.x;                       // b*D + d (scalar)
    const int d   = by % D;                           // scalar
    const int b   = by / D;                           // scalar

    const int w = pix % W;
    const int h = pix / W;

    // ---- ref stats WITHOUT storing f1: m1, n1 in one pass ----
    const float* rb = ref_feats + (size_t)b * C * HW;
    float sum1 = 0.0f, sqr1 = 0.0f;
    #pragma unroll
    for (int c = 0; c < C; ++c) {
        const float rc = rb[c * HW + pix];
        sum1 += rc;
        sqr1 = fmaf(rc, rc, sqr1);
    }
    const float m1 = sum1 * (1.0f / C);
    float sq1 = fmaf(-sum1, m1, sqr1);     // Σ(r-m1)² = Σr² - sum1·m1
    sq1 = fmaxf(sq1, 0.0f);
    const float n1 = sqrtf(sq1);

    const double u = (double)w, v = (double)h;
    const double depth = (double)depths[d];    // scalar load
    float cost = 0.0f;

    #pragma unroll 1   // one source's f64 state live at a time; s uniform
    for (int s = 0; s < S; ++s) {
        const double* Aq = mats + (s * B + b) * 12;   // scalar loads
        const double rx = fma(u, Aq[0], fma(v, Aq[1], Aq[2]));
        const double ry = fma(u, Aq[3], fma(v, Aq[4], Aq[5]));
        const double rz = fma(u, Aq[6], fma(v, Aq[7], Aq[8]));

        const double p0 = fma(depth, rx, Aq[9]);
        const double p1 = fma(depth, ry, Aq[10]);
        const double p2 = fma(depth, rz, Aq[11]);

        const bool valid = p2 > 0.001;
        const double zs = fmax(p2, 0.001);
        // f64 reciprocal: v_rcp_f64 approx + 1 Newton step (>=2^-28 rel)
#if __has_builtin(__builtin_amdgcn_rcp)
        double r = __builtin_amdgcn_rcp(zs);
#else
        double r = (double)__builtin_amdgcn_rcpf((float)zs);
        r = r * fma(-zs, r, 2.0);
#endif
        r = r * fma(-zs, r, 2.0);
        const double x = p0 * r;
        const double y = p1 * r;

        const double x0f = floor(x);
        const double y0f = floor(y);
        // sub-pixel fractions -> f32 (f64 x,y already ~1e-12-accurate)
        const float fx = (float)(x - x0f);
        const float fy = (float)(y - y0f);
        const int x0 = (int)x0f;
        const int y0 = (int)y0f;
        const int x1 = x0 + 1;
        const int y1 = y0 + 1;

        const float gx = 1.0f - fx, gy = 1.0f - fy;
        const bool okx0 = (x0 >= 0) & (x0 < W);
        const bool okx1 = (x1 >= 0) & (x1 < W);
        const bool oky0 = (y0 >= 0) & (y0 < H);
        const bool oky1 = (y1 >= 0) & (y1 < H);
        const float w00 = (valid & okx0 & oky0) ? gx * gy : 0.0f;
        const float w01 = (valid & okx1 & oky0) ? fx * gy : 0.0f;
        const float w10 = (valid & okx0 & oky1) ? gx * fy : 0.0f;
        const float w11 = (valid & okx1 & oky1) ? fx * fy : 0.0f;

        const int x0c = min(max(x0, 0), W - 1);
        const int x1c = min(max(x1, 0), W - 1);
        const int y0c = min(max(y0, 0), H - 1);
        const int y1c = min(max(y1, 0), H - 1);
        const int off00 = y0c * W + x0c;
        const int off01 = y0c * W + x1c;
        const int off10 = y1c * W + x0c;
        const int off11 = y1c * W + x1c;

        // sb wave-uniform -> saddr loads; channel walks in SALU
        const float* sb = src_feats + (size_t)(s * B + b) * C * HW;

        // ---- fused pass: bilinear + shifted-variance stats + rdot ----
        // c = 0 peeled (compile-time shift init).
        float rdot, st = 0.0f, s2 = 0.0f, av;
        {
            const float rc = rb[pix];
            const float val = w00 * sb[off00] + w01 * sb[off01]
                            + w10 * sb[off10] + w11 * sb[off11];
            av = val;
            rdot = rc * val;
        }
        #pragma unroll   // FULL unroll: flat independent load stream
        for (int c = 1; c < C; ++c) {
            const float* p = sb + c * HW;
            const float rc = rb[c * HW + pix];
            const float v00 = p[off00];
            const float v01 = p[off01];
            const float v10 = p[off10];
            const float v11 = p[off11];
            const float val = w00 * v00 + w01 * v01 + w10 * v10 + w11 * v11;
            const float t = val - av;
            st += t;
            s2 = fmaf(t, t, s2);
            rdot = fmaf(rc, val, rdot);
        }
        // Σval = st + C·av ; dot = Σrc·val - m1·Σval ;
        // Σ(f2-m2)² = s2 - st²/C (shifted form; clamp rounding negatives)
        const float sv = fmaf((float)C, av, st);
        const float dot = fmaf(-m1, sv, rdot);
        float sq2 = fmaf(-st * (1.0f / C), st, s2);
        sq2 = fmaxf(sq2, 0.0f);
        cost += dot / (n1 * sqrtf(sq2) + 1e-6f);
    }

    // out base wave-uniform -> saddr store with voffset pix*4
    out[(size_t)by * HW + pix] = cost * (1.0f / S);
}

extern "C" void kernel_launch(void* const* d_in, const int* in_sizes, int n_in,
                              void* d_out, int out_size, void* d_ws, size_t ws_size,
                              hipStream_t stream) {
    const float* ref_feats  = (const float*)d_in[0];
    const float* src_feats  = (const float*)d_in[1];
    const float* ref_intr   = (const float*)d_in[2];
    const float* src_intr   = (const float*)d_in[3];
    const float* ref_to_src = (const float*)d_in[4];
    const float* depths     = (const float*)d_in[5];
    float* out = (float*)d_out;
    double* mats = (double*)d_ws;   // needs SB*12*8 = 576 bytes

    precompute_mats<<<1, 64, 0, stream>>>(ref_intr, src_intr, ref_to_src, mats);

    // Grid TRANSPOSED vs R11: (b,d) fast, pixel tile slow -> consecutive
    // blocks share the same src neighborhood across all 48 depths.
    dim3 grid(B * D, HW / 256);     // 96 x 120, exact
    plane_sweep_kernel<<<grid, dim3(256), 0, stream>>>(
        ref_feats, src_feats, depths, mats, out);
}